// Round 1
// baseline (146.062 us; speedup 1.0000x reference)
//
#include <hip/hip_runtime.h>
#include <hip/hip_bf16.h>
#include <stdint.h>

#define B_   32
#define N_   128
#define E_   8192
#define IMG_ 2048
#define H_   128

typedef __attribute__((ext_vector_type(8))) short bf16x8;
typedef __attribute__((ext_vector_type(4))) float f32x4;

__device__ inline uint16_t f2bf(float x) {
    uint32_t u = __float_as_uint(x);
    uint32_t r = (u + 0x7FFFu + ((u >> 16) & 1u)) >> 16;
    return (uint16_t)r;
}

// ---------------------------------------------------------------------------
// P: transpose + convert weights to bf16, k-major (so B-fragments for
// mfma_f32_16x16x32_bf16 are 8 consecutive bf16 = one 16B load).
// Wt_img[c][k] = W_img[k][c]   (c<128, k<2048)
// Wt_rel[c][k] = W_rel[k][c]   (c<128, k<256; k<128 = src half, k>=128 = dst)
// ---------------------------------------------------------------------------
__global__ void prep_kernel(const float* __restrict__ W_img,
                            const float* __restrict__ W_rel,
                            uint16_t* __restrict__ Wt_img,
                            uint16_t* __restrict__ Wt_rel) {
    int tid = blockIdx.x * blockDim.x + threadIdx.x;
    if (tid < IMG_ * H_) {
        int c = tid / IMG_, k = tid % IMG_;
        Wt_img[tid] = f2bf(W_img[k * H_ + c]);
    } else {
        int t2 = tid - IMG_ * H_;
        if (t2 < 2 * H_ * H_) {
            int c = t2 / 256, k = t2 % 256;
            Wt_rel[t2] = f2bf(W_rel[k * H_ + c]);
        }
    }
}

// ---------------------------------------------------------------------------
// A: img GEMM  [4096 x 2048] @ [2048 x 128], split-K by 4 waves/block,
// fp32 atomicAdd partials into ws img_f32 (pre-zeroed).
// Block = 256 thr (4 waves), each block owns a 16-row strip; wave w does
// K-quarter w. Grid = 256 blocks -> 1024 waves on 1024 SIMDs.
// ---------------------------------------------------------------------------
__global__ __launch_bounds__(256) void img_gemm_kernel(
    const float* __restrict__ img_feat,
    const uint16_t* __restrict__ Wt_img,
    float* __restrict__ img_f32) {
    int strip = blockIdx.x;            // 16 rows per strip
    int w = threadIdx.x >> 6;          // K-quarter 0..3
    int l = threadIdx.x & 63;
    int lr = l & 15;                   // A-row / B-col / D-col lane
    int kl = (l >> 4) * 8;             // k offset within 32-wide K step

    const float* arow = img_feat + (size_t)(strip * 16 + lr) * IMG_;
    f32x4 acc[8];
    #pragma unroll
    for (int n = 0; n < 8; n++) acc[n] = (f32x4){0.f, 0.f, 0.f, 0.f};

    int kbase = w * 512;
    #pragma unroll 4
    for (int ks = 0; ks < 16; ks++) {
        int k = kbase + ks * 32 + kl;
        float4 a0 = *(const float4*)(arow + k);
        float4 a1 = *(const float4*)(arow + k + 4);
        bf16x8 af;
        af[0] = (short)f2bf(a0.x); af[1] = (short)f2bf(a0.y);
        af[2] = (short)f2bf(a0.z); af[3] = (short)f2bf(a0.w);
        af[4] = (short)f2bf(a1.x); af[5] = (short)f2bf(a1.y);
        af[6] = (short)f2bf(a1.z); af[7] = (short)f2bf(a1.w);
        #pragma unroll
        for (int n = 0; n < 8; n++) {
            bf16x8 bf = *(const bf16x8*)(Wt_img + (size_t)(n * 16 + lr) * IMG_ + k);
            acc[n] = __builtin_amdgcn_mfma_f32_16x16x32_bf16(af, bf, acc[n], 0, 0, 0);
        }
    }
    #pragma unroll
    for (int n = 0; n < 8; n++) {
        #pragma unroll
        for (int r = 0; r < 4; r++) {
            int row = strip * 16 + (l >> 4) * 4 + r;   // D row = 4*(l>>4)+r
            int col = n * 16 + lr;                     // D col = lane&15
            atomicAdd(&img_f32[row * H_ + col], acc[n][r]);
        }
    }
}

// ---------------------------------------------------------------------------
// B: node epilogue. img = img_f32 + b_img; loc = img_loc @ W_loc + b_loc
// (K=5, fp32); node_feat = img + loc -> out; img_bf16 = bf16(img) -> ws.
// ---------------------------------------------------------------------------
__global__ void node_kernel(const float* __restrict__ img_f32,
                            const float* __restrict__ img_loc,
                            const float* __restrict__ b_img,
                            const float* __restrict__ W_loc,
                            const float* __restrict__ b_loc,
                            float* __restrict__ out_node,
                            uint16_t* __restrict__ img_bf16) {
    int i = blockIdx.x * blockDim.x + threadIdx.x;   // 0..524287
    int row = i >> 7, col = i & 127;
    float img = img_f32[i] + b_img[col];
    const float* lc = img_loc + row * 5;
    float loc = b_loc[col];
    #pragma unroll
    for (int j = 0; j < 5; j++) loc += lc[j] * W_loc[j * H_ + col];
    out_node[i] = img + loc;
    img_bf16[i] = f2bf(img);
}

// ---------------------------------------------------------------------------
// C: edge GEMM. out[b,e,:] = img[b,src[e],:]@W1 + img[b,dst[e],:]@W2 + b_rel
// = [concat row, K=256] @ Wt_rel. No LDS: A-frags are 16B contiguous loads
// from gathered img_bf16 rows; B-frags 16B loads from L2-resident Wt_rel.
// Block = 4 waves x 32 edges = 128 edges; wave = 32 edges x 128 cols
// (B-frag reused across 2 row strips). Grid = 32 b * 64 etiles = 2048.
// ---------------------------------------------------------------------------
__global__ __launch_bounds__(256) void edge_gemm_kernel(
    const uint16_t* __restrict__ img_bf16,
    const uint16_t* __restrict__ Wt_rel,
    const int* __restrict__ edge_src,
    const int* __restrict__ edge_dst,
    const float* __restrict__ b_rel,
    float* __restrict__ out_edge) {
    int bid = blockIdx.x;
    int b = bid >> 6;
    int etile = bid & 63;
    int w = threadIdx.x >> 6;
    int l = threadIdx.x & 63;
    int lr = l & 15;
    int kl = (l >> 4) * 8;

    int e0 = etile * 128 + w * 32 + lr;   // strip 0 row for this lane
    int e1 = e0 + 16;                     // strip 1 row
    const uint16_t* base = img_bf16 + (size_t)b * N_ * H_;
    const uint16_t* s0 = base + edge_src[e0] * H_;
    const uint16_t* d0 = base + edge_dst[e0] * H_;
    const uint16_t* s1 = base + edge_src[e1] * H_;
    const uint16_t* d1 = base + edge_dst[e1] * H_;

    f32x4 acc[2][8];
    #pragma unroll
    for (int n = 0; n < 8; n++) {
        float br = b_rel[n * 16 + lr];
        acc[0][n] = (f32x4){br, br, br, br};
        acc[1][n] = acc[0][n];
    }

    #pragma unroll
    for (int ks = 0; ks < 8; ks++) {
        int klo = (ks & 3) * 32 + kl;     // within-half k (A rows are 128 wide)
        int kgl = ks * 32 + kl;           // global k in [0,256) for Wt_rel
        const uint16_t* p0 = (ks < 4) ? s0 : d0;
        const uint16_t* p1 = (ks < 4) ? s1 : d1;
        bf16x8 a0 = *(const bf16x8*)(p0 + klo);
        bf16x8 a1 = *(const bf16x8*)(p1 + klo);
        #pragma unroll
        for (int n = 0; n < 8; n++) {
            bf16x8 bf = *(const bf16x8*)(Wt_rel + (size_t)(n * 16 + lr) * 256 + kgl);
            acc[0][n] = __builtin_amdgcn_mfma_f32_16x16x32_bf16(a0, bf, acc[0][n], 0, 0, 0);
            acc[1][n] = __builtin_amdgcn_mfma_f32_16x16x32_bf16(a1, bf, acc[1][n], 0, 0, 0);
        }
    }

    size_t outb = ((size_t)b * E_ + (size_t)etile * 128 + w * 32) * H_;
    #pragma unroll
    for (int s = 0; s < 2; s++) {
        #pragma unroll
        for (int n = 0; n < 8; n++) {
            #pragma unroll
            for (int r = 0; r < 4; r++) {
                int e_local = s * 16 + (l >> 4) * 4 + r;
                out_edge[outb + (size_t)e_local * H_ + n * 16 + lr] = acc[s][n][r];
            }
        }
    }
}

// ---------------------------------------------------------------------------
extern "C" void kernel_launch(void* const* d_in, const int* in_sizes, int n_in,
                              void* d_out, int out_size, void* d_ws, size_t ws_size,
                              hipStream_t stream) {
    const float* img_feat = (const float*)d_in[0];
    const float* img_loc  = (const float*)d_in[1];
    const int*   edge_src = (const int*)d_in[2];
    const int*   edge_dst = (const int*)d_in[3];
    const float* W_img    = (const float*)d_in[4];
    const float* b_img    = (const float*)d_in[5];
    const float* W_loc    = (const float*)d_in[6];
    const float* b_loc    = (const float*)d_in[7];
    const float* W_rel    = (const float*)d_in[8];
    const float* b_rel    = (const float*)d_in[9];

    float* out_node = (float*)d_out;                       // [B,N,H]
    float* out_edge = out_node + (size_t)B_ * N_ * H_;     // [B,E,H]

    // workspace layout
    char* ws = (char*)d_ws;
    float*    img_f32  = (float*)ws;                                   // 2 MB
    uint16_t* Wt_img   = (uint16_t*)(ws + 2097152);                    // 512 KB
    uint16_t* Wt_rel   = (uint16_t*)(ws + 2097152 + 524288);           // 64 KB
    uint16_t* img_bf16 = (uint16_t*)(ws + 2097152 + 524288 + 65536);   // 1 MB

    hipMemsetAsync(img_f32, 0, (size_t)B_ * N_ * H_ * sizeof(float), stream);

    prep_kernel<<<dim3((IMG_ * H_ + 2 * H_ * H_) / 256), dim3(256), 0, stream>>>(
        W_img, W_rel, Wt_img, Wt_rel);

    img_gemm_kernel<<<dim3(256), dim3(256), 0, stream>>>(img_feat, Wt_img, img_f32);

    node_kernel<<<dim3((B_ * N_ * H_) / 256), dim3(256), 0, stream>>>(
        img_f32, img_loc, b_img, W_loc, b_loc, out_node, img_bf16);

    edge_gemm_kernel<<<dim3(B_ * (E_ / 128)), dim3(256), 0, stream>>>(
        img_bf16, Wt_rel, edge_src, edge_dst, b_rel, out_edge);
}

// Round 2
// 58.004 us; speedup vs baseline: 2.5181x; 2.5181x over previous
//
#include <hip/hip_runtime.h>
#include <hip/hip_bf16.h>
#include <stdint.h>

#define B_   32
#define N_   128
#define E_   8192
#define IMG_ 2048
#define H_   128

typedef __attribute__((ext_vector_type(8))) short bf16x8;
typedef __attribute__((ext_vector_type(4))) float f32x4;

__device__ inline uint16_t f2bf(float x) {
    uint32_t u = __float_as_uint(x);
    uint32_t r = (u + 0x7FFFu + ((u >> 16) & 1u)) >> 16;
    return (uint16_t)r;
}
__device__ inline float bf2f(short x) {
    return __uint_as_float(((uint32_t)(uint16_t)x) << 16);
}

// ---------------------------------------------------------------------------
// P: transpose + convert weights to bf16, k-major.
// Wt_img[c][k] = W_img[k][c]   (c<128, k<2048)
// Wt_rel[c][k] = W_rel[k][c]   (c<128, k<256; k<128 = W1 rows, k>=128 = W2)
// ---------------------------------------------------------------------------
__global__ void prep_kernel(const float* __restrict__ W_img,
                            const float* __restrict__ W_rel,
                            uint16_t* __restrict__ Wt_img,
                            uint16_t* __restrict__ Wt_rel) {
    int tid = blockIdx.x * blockDim.x + threadIdx.x;
    if (tid < IMG_ * H_) {
        int c = tid / IMG_, k = tid % IMG_;
        Wt_img[tid] = f2bf(W_img[k * H_ + c]);
    } else {
        int t2 = tid - IMG_ * H_;
        if (t2 < 2 * H_ * H_) {
            int c = t2 / 256, k = t2 % 256;
            Wt_rel[t2] = f2bf(W_rel[k * H_ + c]);
        }
    }
}

// ---------------------------------------------------------------------------
// NODE+PROJ fused: one block per 16-row strip of the 4096 (b,n) rows.
// 1024 thr = 16 waves.
// Phase 1: img GEMM, wave w owns K-slice [w*128, w*128+128), acc in regs.
// Phase 2: waves dump partials to LDS red[16][16][128] (128 KB).
// Phase 3: 16-way reduce (bank = col -> conflict-free), + b_img, + loc path,
//          write node_feat; stash bf16 img strip in LDS (aliased over red,
//          guarded by barriers).
// Phase 4: proj GEMM (K=128): wave w owns output cols [w*16, w*16+16) of 256;
//          cols<128 = img@W1 + b_rel, cols>=128 = img@W2. bf16 out (2 MB).
// ---------------------------------------------------------------------------
__global__ __launch_bounds__(1024) void node_proj_kernel(
    const float* __restrict__ img_feat,
    const uint16_t* __restrict__ Wt_img,
    const uint16_t* __restrict__ Wt_rel,
    const float* __restrict__ img_loc,
    const float* __restrict__ b_img,
    const float* __restrict__ W_loc,
    const float* __restrict__ b_loc,
    const float* __restrict__ b_rel,
    float* __restrict__ out_node,
    uint16_t* __restrict__ proj) {
    __shared__ __align__(16) char lds_raw[131072];
    float (*red)[16][128] = (float (*)[16][128])lds_raw;     // [16][16][128] f32
    uint16_t (*imgb)[136] = (uint16_t (*)[136])lds_raw;      // [16][136] bf16 (aliased)

    int strip = blockIdx.x;
    int w  = threadIdx.x >> 6;     // wave 0..15 = K-slice
    int l  = threadIdx.x & 63;
    int lr = l & 15;
    int kq = l >> 4;
    int kl = kq * 8;

    // ---- phase 1: split-K GEMM ----
    const float* arow = img_feat + (size_t)(strip * 16 + lr) * IMG_;
    f32x4 acc[8];
    #pragma unroll
    for (int n = 0; n < 8; n++) acc[n] = (f32x4){0.f, 0.f, 0.f, 0.f};
    int k0 = w * 128;
    #pragma unroll
    for (int ks = 0; ks < 4; ks++) {
        int k = k0 + ks * 32 + kl;
        float4 a0 = *(const float4*)(arow + k);
        float4 a1 = *(const float4*)(arow + k + 4);
        bf16x8 af;
        af[0] = (short)f2bf(a0.x); af[1] = (short)f2bf(a0.y);
        af[2] = (short)f2bf(a0.z); af[3] = (short)f2bf(a0.w);
        af[4] = (short)f2bf(a1.x); af[5] = (short)f2bf(a1.y);
        af[6] = (short)f2bf(a1.z); af[7] = (short)f2bf(a1.w);
        #pragma unroll
        for (int n = 0; n < 8; n++) {
            bf16x8 bf = *(const bf16x8*)(Wt_img + (size_t)(n * 16 + lr) * IMG_ + k);
            acc[n] = __builtin_amdgcn_mfma_f32_16x16x32_bf16(af, bf, acc[n], 0, 0, 0);
        }
    }

    // ---- phase 2: dump partials ----
    #pragma unroll
    for (int n = 0; n < 8; n++)
        #pragma unroll
        for (int r = 0; r < 4; r++)
            red[w][kq * 4 + r][n * 16 + lr] = acc[n][r];
    __syncthreads();

    // ---- phase 3: reduce + epilogue ----
    int tid  = threadIdx.x;
    int row0 = tid >> 7, col = tid & 127;    // rows 0..7
    int row1 = row0 + 8;                     // rows 8..15
    float s0 = 0.f, s1 = 0.f;
    #pragma unroll
    for (int ww = 0; ww < 16; ww++) {
        s0 += red[ww][row0][col];
        s1 += red[ww][row1][col];
    }
    __syncthreads();   // all red reads done before imgb overwrites it

    {
        float bi = b_img[col];
        float bl = b_loc[col];
        float wl[5];
        #pragma unroll
        for (int j = 0; j < 5; j++) wl[j] = W_loc[j * H_ + col];

        float img0 = s0 + bi, img1 = s1 + bi;
        int g0 = strip * 16 + row0, g1 = strip * 16 + row1;
        const float* lc0 = img_loc + g0 * 5;
        const float* lc1 = img_loc + g1 * 5;
        float loc0 = bl, loc1 = bl;
        #pragma unroll
        for (int j = 0; j < 5; j++) { loc0 += lc0[j] * wl[j]; loc1 += lc1[j] * wl[j]; }
        out_node[(size_t)g0 * H_ + col] = img0 + loc0;
        out_node[(size_t)g1 * H_ + col] = img1 + loc1;
        imgb[row0][col] = f2bf(img0);
        imgb[row1][col] = f2bf(img1);
    }
    __syncthreads();   // imgb visible

    // ---- phase 4: proj GEMM (K=128, 256 output cols, wave w -> 16 cols) ----
    int cp = w * 16 + lr;    // output col in [0,256)
    const uint16_t* bbase = (cp < 128)
        ? (Wt_rel + (size_t)cp * 256)
        : (Wt_rel + (size_t)(cp - 128) * 256 + 128);
    f32x4 pacc = (f32x4){0.f, 0.f, 0.f, 0.f};
    #pragma unroll
    for (int ks = 0; ks < 4; ks++) {
        int k = ks * 32 + kl;
        bf16x8 af = *(const bf16x8*)(&imgb[lr][k]);
        bf16x8 bf = *(const bf16x8*)(bbase + k);
        pacc = __builtin_amdgcn_mfma_f32_16x16x32_bf16(af, bf, pacc, 0, 0, 0);
    }
    float brel = (cp < 128) ? b_rel[cp] : 0.f;
    #pragma unroll
    for (int r = 0; r < 4; r++) {
        int grow = strip * 16 + kq * 4 + r;
        proj[(size_t)grow * 256 + cp] = f2bf(pacc[r] + brel);
    }
}

// ---------------------------------------------------------------------------
// EDGE stream: out[b,e,c] = proj[b*128+src[e]][c] + proj[b*128+dst[e]][128+c]
// (b_rel folded into proj src half). Pure gather-add: reads 2 MB L2-resident
// table, writes 134 MB coalesced. 8 elems (32 B out) per thread-iter.
// ---------------------------------------------------------------------------
__global__ __launch_bounds__(256) void edge_kernel(
    const uint16_t* __restrict__ proj,
    const int* __restrict__ edge_src,
    const int* __restrict__ edge_dst,
    float* __restrict__ out_edge) {
    int t = blockIdx.x * 256 + threadIdx.x;     // 524288 threads
    #pragma unroll
    for (int it = 0; it < 8; it++) {
        int g = t + it * 524288;                // 8-elem group id, 4.19M total
        int b = g >> 17;                        // 131072 groups per batch
        int r = g & 131071;
        int e = r >> 4;                         // 16 groups per edge
        int c = (r & 15) * 8;
        int s = edge_src[e];
        int d = edge_dst[e];
        bf16x8 a  = *(const bf16x8*)(proj + (((size_t)b * N_ + s) * 256 + c));
        bf16x8 bb = *(const bf16x8*)(proj + (((size_t)b * N_ + d) * 256 + 128 + c));
        float* op = out_edge + ((size_t)b * E_ + e) * (size_t)H_ + c;
        float4 o0, o1;
        o0.x = bf2f(a[0]) + bf2f(bb[0]);
        o0.y = bf2f(a[1]) + bf2f(bb[1]);
        o0.z = bf2f(a[2]) + bf2f(bb[2]);
        o0.w = bf2f(a[3]) + bf2f(bb[3]);
        o1.x = bf2f(a[4]) + bf2f(bb[4]);
        o1.y = bf2f(a[5]) + bf2f(bb[5]);
        o1.z = bf2f(a[6]) + bf2f(bb[6]);
        o1.w = bf2f(a[7]) + bf2f(bb[7]);
        *(float4*)op = o0;
        *(float4*)(op + 4) = o1;
    }
}

// ---------------------------------------------------------------------------
extern "C" void kernel_launch(void* const* d_in, const int* in_sizes, int n_in,
                              void* d_out, int out_size, void* d_ws, size_t ws_size,
                              hipStream_t stream) {
    const float* img_feat = (const float*)d_in[0];
    const float* img_loc  = (const float*)d_in[1];
    const int*   edge_src = (const int*)d_in[2];
    const int*   edge_dst = (const int*)d_in[3];
    const float* W_img    = (const float*)d_in[4];
    const float* b_img    = (const float*)d_in[5];
    const float* W_loc    = (const float*)d_in[6];
    const float* b_loc    = (const float*)d_in[7];
    const float* W_rel    = (const float*)d_in[8];
    const float* b_rel    = (const float*)d_in[9];

    float* out_node = (float*)d_out;                       // [B,N,H]
    float* out_edge = out_node + (size_t)B_ * N_ * H_;     // [B,E,H]

    // workspace: Wt_img 512KB | Wt_rel 64KB | proj 2MB  (total 2.625 MB)
    char* ws = (char*)d_ws;
    uint16_t* Wt_img = (uint16_t*)ws;
    uint16_t* Wt_rel = (uint16_t*)(ws + 524288);
    uint16_t* proj   = (uint16_t*)(ws + 524288 + 65536);   // [4096][256] bf16

    prep_kernel<<<dim3((IMG_ * H_ + 2 * H_ * H_) / 256), dim3(256), 0, stream>>>(
        W_img, W_rel, Wt_img, Wt_rel);

    node_proj_kernel<<<dim3(256), dim3(1024), 0, stream>>>(
        img_feat, Wt_img, Wt_rel, img_loc, b_img, W_loc, b_loc, b_rel,
        out_node, proj);

    edge_kernel<<<dim3(2048), dim3(256), 0, stream>>>(
        proj, edge_src, edge_dst, out_edge);
}